// Round 4
// baseline (793.132 us; speedup 1.0000x reference)
//
#include <hip/hip_runtime.h>
#include <stdint.h>

// Problem constants: B=128, D=512, N_ENVS=4, k = int(0.1*512*512) = 26214.
#define D_DIM   512
#define DD      262144                    // D*D
#define DD4     65536                     // DD / 4 (float4 groups)
#define B_DIM   128
#define N_ENVS  4
#define K_SEL   26214
#define BDD     33554432u                 // B*D*D
#define NBLK    64                        // hist/gather blocks per env
#define CAP2    98304                     // max gathered pairs per env (expect ~28K: byte-bin [0.125,0.5))
#define CAP3    4096                      // max in-LDS pairs for final rank select (expect ~450)

typedef float nfloat4 __attribute__((ext_vector_type(4)));

// ---- workspace layout (bytes) ----
// [0,32)        thrcut[4][2]  {threshold key, cutoff idx}
// [64,96)       pk[4][2]      {prefix byte-bin, krem8}
// [128,144)     cnt8[4]
// [144,148)     ticket        (last-block counter for inline select)
// [4096,+256K)  histp[NBLK][N_ENVS][256] u32 per-block partial hists
// [512K,+3M)    pairs8[4][CAP2] (uint2)
#define PK_OFF      64
#define CNT_OFF     128
#define TICKET_OFF  144
#define HISTP_OFF   4096
#define PAIRS_OFF   (512 * 1024)
#define PAIRS_BYTES ((size_t)N_ENVS * CAP2 * 8)
#define SEL_NEED    (PAIRS_OFF + PAIRS_BYTES)

__device__ __forceinline__ uint32_t fkey(float f) {
    uint32_t u = __float_as_uint(f);
    return (u & 0x80000000u) ? ~u : (u | 0x80000000u);
}
__device__ __forceinline__ float sigmoidf_(float x) {
    return 1.0f / (1.0f + __expf(-x));
}

// ---- M1: top-8-bit histogram of keys, per env. grid (64, 4) x 256. ----
// Per-block partial hists (plain stores, no pre-zero). Zeroes cnt8 + ticket
// (stream-ordered before gather8 uses them).
__global__ __launch_bounds__(256) void hist8_kernel(
    const float* __restrict__ base, const float* __restrict__ deltas,
    uint32_t* __restrict__ histp, uint32_t* __restrict__ cnt8,
    uint32_t* __restrict__ ticket)
{
    int e = blockIdx.y;
    const float4* b4 = (const float4*)base;
    const float4* d4 = (const float4*)(deltas + (size_t)e * DD);
    __shared__ uint32_t s_h[256];
    int tid = threadIdx.x;
    s_h[tid] = 0;
    if (blockIdx.x == 0 && tid == 0) {
        cnt8[e] = 0;
        if (e == 0) *ticket = 0;
    }
    __syncthreads();
    int g0 = blockIdx.x * 256 + tid;                 // float4 group
    #pragma unroll
    for (int r = 0; r < 4; ++r) {
        int g = g0 + r * 16384;                      // 64 blocks * 256 threads
        float4 bv = b4[g], dv = d4[g];
        atomicAdd(&s_h[fkey(bv.x + dv.x) >> 24], 1u);
        atomicAdd(&s_h[fkey(bv.y + dv.y) >> 24], 1u);
        atomicAdd(&s_h[fkey(bv.z + dv.z) >> 24], 1u);
        atomicAdd(&s_h[fkey(bv.w + dv.w) >> 24], 1u);
    }
    __syncthreads();
    histp[(blockIdx.x * N_ENVS + e) * 256 + tid] = s_h[tid];
}

// ---- M2: pick byte-bin P per env; gather (key,idx) pairs; the LAST block ----
// ---- (device-wide ticket) runs the exact rank select inline -> thrcut. ----
// grid (64, 4) x 256.
__global__ __launch_bounds__(256) void gather_sel_kernel(
    const float* __restrict__ base, const float* __restrict__ deltas,
    const uint32_t* __restrict__ histp, uint32_t* __restrict__ pk,
    uint32_t* __restrict__ cnt8, uint2* __restrict__ pairs8,
    uint32_t* __restrict__ ticket, uint32_t* __restrict__ thrcut)
{
    int e = blockIdx.y;
    const float4* b4 = (const float4*)base;
    const float4* d4 = (const float4*)(deltas + (size_t)e * DD);
    uint2* pp = pairs8 + (size_t)e * CAP2;
    __shared__ uint32_t s_h[256];
    __shared__ uint32_t s_scan[256];
    __shared__ uint2    s_pairs[CAP3];               // 32 KB, last-block select only
    __shared__ uint32_t s_P, s_base, s_cnt, s_b16, s_krem16, s_last;
    int tid = threadIdx.x;

    // Sum the 64 per-block partials for my bin (coalesced per j).
    uint32_t sum = 0;
    #pragma unroll 8
    for (int j = 0; j < NBLK; ++j)
        sum += histp[(j * N_ENVS + e) * 256 + tid];
    s_h[tid] = sum;
    __syncthreads();
    if (tid == 0) {
        uint32_t cum = 0;
        for (int b = 255; b >= 0; --b) {
            uint32_t c = s_h[b];
            if (cum + c >= (uint32_t)K_SEL) {
                s_P = (uint32_t)b;
                if (blockIdx.x == 0) {
                    pk[2 * e + 0] = (uint32_t)b;
                    pk[2 * e + 1] = (uint32_t)K_SEL - cum;   // krem8 >= 1
                }
                break;
            }
            cum += c;
        }
    }
    __syncthreads();
    uint32_t P = s_P;

    // Phase 1: compute keys once, keep in registers, count my matches.
    int g0 = blockIdx.x * 256 + tid;
    uint32_t keys[16];
    uint32_t m = 0;
    #pragma unroll
    for (int r = 0; r < 4; ++r) {
        int g = g0 + r * 16384;
        float4 bv = b4[g], dv = d4[g];
        uint32_t c0 = fkey(bv.x + dv.x), c1 = fkey(bv.y + dv.y);
        uint32_t c2 = fkey(bv.z + dv.z), c3 = fkey(bv.w + dv.w);
        keys[r*4+0]=c0; keys[r*4+1]=c1; keys[r*4+2]=c2; keys[r*4+3]=c3;
        m += ((c0>>24)==P) + ((c1>>24)==P) + ((c2>>24)==P) + ((c3>>24)==P);
    }
    // Inclusive Hillis-Steele scan over 256 threads.
    s_scan[tid] = m;
    __syncthreads();
    #pragma unroll
    for (int off = 1; off < 256; off <<= 1) {
        uint32_t v = (tid >= off) ? s_scan[tid - off] : 0u;
        __syncthreads();
        s_scan[tid] += v;
        __syncthreads();
    }
    uint32_t excl = s_scan[tid] - m;
    if (tid == 255) s_base = atomicAdd(&cnt8[e], s_scan[255]);
    __syncthreads();
    uint32_t pos = s_base + excl;

    // Phase 2: scatter straight from registers.
    #pragma unroll
    for (int r = 0; r < 4; ++r) {
        int g = g0 + r * 16384;
        #pragma unroll
        for (int j = 0; j < 4; ++j) {
            uint32_t key = keys[r * 4 + j];
            if ((key >> 24) == P) {
                if (pos < CAP2) pp[pos] = make_uint2(key, (uint32_t)(g * 4 + j));
                ++pos;
            }
        }
    }

    // ---- Last-block inline select (canonical threadfence+ticket pattern) ----
    __threadfence();                                 // release my pair stores
    __syncthreads();                                 // all threads' stores fenced
    if (tid == 0)
        s_last = (atomicAdd(ticket, 1u) == (uint32_t)(NBLK * N_ENVS - 1));
    __syncthreads();
    if (!s_last) return;
    __threadfence();                                 // acquire other blocks' stores

    // This block now does select2's job for all 4 envs (reads all from global).
    for (int e2 = 0; e2 < N_ENVS; ++e2) {
        const uint2* qq = pairs8 + (size_t)e2 * CAP2;
        uint32_t M = cnt8[e2]; if (M > CAP2) M = CAP2;
        uint32_t krem8 = pk[2 * e2 + 1];

        s_h[tid] = 0;
        if (tid == 0) s_cnt = 0;
        __syncthreads();
        // hist of bits 16-23 within the byte-bin.
        for (uint32_t j = tid; j < M; j += 256)
            atomicAdd(&s_h[(qq[j].x >> 16) & 255u], 1u);
        __syncthreads();
        if (tid == 0) {
            uint32_t cum = 0;
            for (int b = 255; b >= 0; --b) {
                uint32_t c = s_h[b];
                if (cum + c >= krem8) { s_b16 = (uint32_t)b; s_krem16 = krem8 - cum; break; }
                cum += c;
            }
        }
        __syncthreads();
        uint32_t b16 = s_b16;
        for (uint32_t j = tid; j < M; j += 256) {
            uint2 p = qq[j];
            if (((p.x >> 16) & 255u) == b16) {
                uint32_t q = atomicAdd(&s_cnt, 1u);
                if (q < CAP3) s_pairs[q] = p;
            }
        }
        __syncthreads();
        uint32_t M2 = s_cnt; if (M2 > CAP3) M2 = CAP3;
        uint32_t target = s_krem16 - 1;              // 0-based rank
        for (uint32_t j = tid; j < M2; j += 256) {
            uint2 me = s_pairs[j];
            uint32_t rank = 0;
            for (uint32_t l = 0; l < M2; ++l) {
                uint2 o = s_pairs[l];
                rank += (o.x > me.x) || (o.x == me.x && o.y < me.y);
            }
            if (rank == target) {
                thrcut[2 * e2 + 0] = me.x;
                thrcut[2 * e2 + 1] = me.y;
            }
        }
        __syncthreads();                             // s_h/s_cnt reuse next env
    }
}

// ---- M3: compute-once-per-env in registers, broadcast to rows. ----
// grid (256, 8) x 256. Identical to verified round-2 kernel except env_idx
// is staged in LDS (removes 15 dependent scalar global loads per thread).
__global__ __launch_bounds__(256) void write_bcast_kernel(
    const int* __restrict__ env_idx, const float* __restrict__ base,
    const float* __restrict__ deltas, const uint32_t* __restrict__ thrcut,
    float* __restrict__ out)
{
    __shared__ int s_env[B_DIM];
    int tid = threadIdx.x;
    if (tid < B_DIM) s_env[tid] = env_idx[tid];

    int g = blockIdx.x * 256 + tid;                  // float4 group in [0, DD4)
    uint32_t i0 = (uint32_t)g * 4u;
    float4 bv = ((const float4*)base)[g];

    nfloat4 lgv[N_ENVS], sgv[N_ENVS], avv[N_ENVS];   // static indexing only
    #pragma unroll
    for (int e = 0; e < N_ENVS; ++e) {
        float4 dv = ((const float4*)(deltas + (size_t)e * DD))[g];
        uint32_t T = thrcut[2 * e], C = thrcut[2 * e + 1];
        nfloat4 lg = { bv.x + dv.x, bv.y + dv.y, bv.z + dv.z, bv.w + dv.w };
        nfloat4 sg = { sigmoidf_(lg.x), sigmoidf_(lg.y),
                       sigmoidf_(lg.z), sigmoidf_(lg.w) };
        uint32_t kx = fkey(lg.x), ky = fkey(lg.y);
        uint32_t kz = fkey(lg.z), kw = fkey(lg.w);
        nfloat4 av;
        av.x = (kx > T || (kx == T && i0 + 0u <= C)) ? sg.x : 0.0f;
        av.y = (ky > T || (ky == T && i0 + 1u <= C)) ? sg.y : 0.0f;
        av.z = (kz > T || (kz == T && i0 + 2u <= C)) ? sg.z : 0.0f;
        av.w = (kw > T || (kw == T && i0 + 3u <= C)) ? sg.w : 0.0f;
        lgv[e] = lg; sgv[e] = sg; avv[e] = av;
    }
    __syncthreads();

    const int ROWS = B_DIM / 8;                      // 16 rows per y-block
    int b0 = blockIdx.y * ROWS;
    nfloat4* o0 = (nfloat4*)out + g;
    #pragma unroll 4
    for (int bb = 0; bb < ROWS; ++bb) {
        int b = b0 + bb;
        int e = s_env[b];                            // wave-uniform (LDS)
        nfloat4* o = o0 + (size_t)b * DD4;
        switch (e) {                                 // uniform branch, static reg idx
        case 0: o[0] = avv[0]; o[BDD/4] = lgv[0]; o[2*(BDD/4)] = sgv[0]; break;
        case 1: o[0] = avv[1]; o[BDD/4] = lgv[1]; o[2*(BDD/4)] = sgv[1]; break;
        case 2: o[0] = avv[2]; o[BDD/4] = lgv[2]; o[2*(BDD/4)] = sgv[2]; break;
        default: o[0] = avv[3]; o[BDD/4] = lgv[3]; o[2*(BDD/4)] = sgv[3]; break;
        }
    }
}

extern "C" void kernel_launch(void* const* d_in, const int* in_sizes, int n_in,
                              void* d_out, int out_size, void* d_ws, size_t ws_size,
                              hipStream_t stream) {
    // inputs: 0=z_s (unused), 1=env_idx (int32), 2=A_base (f32), 3=A_deltas (f32)
    const int*   env_idx  = (const int*)d_in[1];
    const float* A_base   = (const float*)d_in[2];
    const float* A_deltas = (const float*)d_in[3];
    float* out = (float*)d_out;

    uint32_t* thrcut = (uint32_t*)d_ws;   // 32 B, must survive to the final write

    char* scratch;
    if (ws_size >= SEL_NEED) {
        scratch = (char*)d_ws;
    } else {
        // Carve selection scratch from d_out's tail; it is dead before the
        // final write rewrites every output element (stream-ordered).
        size_t out_bytes = (size_t)out_size * sizeof(float);
        scratch = (char*)d_out + ((out_bytes - SEL_NEED) & ~(size_t)255);
    }
    uint32_t* pk     = (uint32_t*)(scratch + PK_OFF);
    uint32_t* cnt8   = (uint32_t*)(scratch + CNT_OFF);
    uint32_t* ticket = (uint32_t*)(scratch + TICKET_OFF);
    uint32_t* histp  = (uint32_t*)(scratch + HISTP_OFF);
    uint2*    pairs8 = (uint2*)   (scratch + PAIRS_OFF);

    // No memset: histp uses plain per-block stores; cnt8 + ticket are zeroed
    // by hist8 (stream-ordered); pk/thrcut written unconditionally every run.
    hist8_kernel<<<dim3(NBLK, N_ENVS), 256, 0, stream>>>(
        A_base, A_deltas, histp, cnt8, ticket);
    gather_sel_kernel<<<dim3(NBLK, N_ENVS), 256, 0, stream>>>(
        A_base, A_deltas, histp, pk, cnt8, pairs8, ticket, thrcut);
    write_bcast_kernel<<<dim3(DD4 / 256, 8), 256, 0, stream>>>(
        env_idx, A_base, A_deltas, thrcut, out);
}

// Round 5
// 446.743 us; speedup vs baseline: 1.7754x; 1.7754x over previous
//
#include <hip/hip_runtime.h>
#include <stdint.h>

// Problem constants: B=128, D=512, N_ENVS=4, k = int(0.1*512*512) = 26214.
#define D_DIM   512
#define DD      262144                    // D*D
#define DD4     65536                     // DD / 4 (float4 groups)
#define B_DIM   128
#define N_ENVS  4
#define K_SEL   26214
#define BDD     33554432u                 // B*D*D
#define NBLK    64                        // hist/gather blocks per env
#define CAP2    98304                     // max gathered pairs per env (expect ~28K: byte-bin [0.125,0.5))
#define CAP3    4096                      // max in-LDS pairs for final rank select (expect ~450)

typedef float nfloat4 __attribute__((ext_vector_type(4)));

// ---- workspace layout (bytes) ----
// [0,32)        thrcut[4][2]  {threshold key, cutoff idx}
// [64,96)       pk[4][2]      {prefix byte-bin, krem8}
// [128,144)     cnt8[4]
// [4096,+256K)  histp[NBLK][N_ENVS][256] u32 per-block partial hists
// [512K,+3.5M)  pairs8[4][CAP2] (uint2)
#define PK_OFF      64
#define CNT_OFF     128
#define HISTP_OFF   4096
#define PAIRS_OFF   (512 * 1024)
#define PAIRS_BYTES ((size_t)N_ENVS * CAP2 * 8)
#define SEL_NEED    (PAIRS_OFF + PAIRS_BYTES)

#define SEL_BLOCKS  (NBLK * N_ENVS)       // 256 selection blocks in K1/K2
#define WR_BLOCKS   1024                  // 256 chunks x 4 bands (16 rows each)

__device__ __forceinline__ uint32_t fkey(float f) {
    uint32_t u = __float_as_uint(f);
    return (u & 0x80000000u) ? ~u : (u | 0x80000000u);
}
__device__ __forceinline__ float sigmoidf_(float x) {
    return 1.0f / (1.0f + __expf(-x));
}

// Shared body: write logits+soft planes for a 16-row band h, chunk c.
// (thrcut-independent -> can run concurrently with selection blocks.)
__device__ __forceinline__ void write_lgsg_band(
    const int* __restrict__ env_idx, const float* __restrict__ base,
    const float* __restrict__ deltas, float* __restrict__ out,
    int c, int h, int tid)
{
    __shared__ int s_env[16];
    if (tid < 16) s_env[tid] = env_idx[h * 16 + tid];
    int g = c * 256 + tid;                            // float4 group
    float4 bv = ((const float4*)base)[g];
    nfloat4 lgv[N_ENVS], sgv[N_ENVS];                 // static indexing only
    #pragma unroll
    for (int e = 0; e < N_ENVS; ++e) {
        float4 dv = ((const float4*)(deltas + (size_t)e * DD))[g];
        nfloat4 lg = { bv.x + dv.x, bv.y + dv.y, bv.z + dv.z, bv.w + dv.w };
        lgv[e] = lg;
        sgv[e] = nfloat4{ sigmoidf_(lg.x), sigmoidf_(lg.y),
                          sigmoidf_(lg.z), sigmoidf_(lg.w) };
    }
    __syncthreads();
    nfloat4* o0 = (nfloat4*)out + g;
    #pragma unroll 4
    for (int bb = 0; bb < 16; ++bb) {
        int b = h * 16 + bb;
        int e = s_env[bb];                            // block-uniform
        nfloat4* o = o0 + (size_t)b * DD4;
        switch (e) {                                  // uniform branch, static reg idx
        case 0:  o[BDD/4] = lgv[0]; o[2*(BDD/4)] = sgv[0]; break;
        case 1:  o[BDD/4] = lgv[1]; o[2*(BDD/4)] = sgv[1]; break;
        case 2:  o[BDD/4] = lgv[2]; o[2*(BDD/4)] = sgv[2]; break;
        default: o[BDD/4] = lgv[3]; o[2*(BDD/4)] = sgv[3]; break;
        }
    }
}

// ---- K1: blocks [0,256) = hist8 (round-2 body); blocks [256,1280) = ----
// ---- logits/soft planes for rows 0..63 (overlaps the hist latency). ----
__global__ __launch_bounds__(256) void k1_hist_lgsg(
    const int* __restrict__ env_idx, const float* __restrict__ base,
    const float* __restrict__ deltas, uint32_t* __restrict__ histp,
    uint32_t* __restrict__ cnt8, float* __restrict__ out)
{
    int bid = blockIdx.x;
    int tid = threadIdx.x;
    if (bid < SEL_BLOCKS) {
        int e = bid & (N_ENVS - 1);
        int s = bid >> 2;                             // slice 0..63
        const float4* b4 = (const float4*)base;
        const float4* d4 = (const float4*)(deltas + (size_t)e * DD);
        __shared__ uint32_t s_h[256];
        s_h[tid] = 0;
        if (s == 0 && tid == 0) cnt8[e] = 0;
        __syncthreads();
        int g0 = s * 256 + tid;
        #pragma unroll
        for (int r = 0; r < 4; ++r) {
            int g = g0 + r * 16384;                   // 64 slices * 256 threads
            float4 bv = b4[g], dv = d4[g];
            atomicAdd(&s_h[fkey(bv.x + dv.x) >> 24], 1u);
            atomicAdd(&s_h[fkey(bv.y + dv.y) >> 24], 1u);
            atomicAdd(&s_h[fkey(bv.z + dv.z) >> 24], 1u);
            atomicAdd(&s_h[fkey(bv.w + dv.w) >> 24], 1u);
        }
        __syncthreads();
        histp[(s * N_ENVS + e) * 256 + tid] = s_h[tid];
    } else {
        int w = bid - SEL_BLOCKS;                     // 0..1023
        int c = w & 255;                              // chunk
        int h = w >> 8;                               // band 0..3 -> rows 0..63
        write_lgsg_band(env_idx, base, deltas, out, c, h, tid);
    }
}

// ---- K2: blocks [0,256) = gather8 (round-2 body, keys-in-regs); blocks ----
// ---- [256,1280) = logits/soft planes for rows 64..127. ----
__global__ __launch_bounds__(256) void k2_gather_lgsg(
    const int* __restrict__ env_idx, const float* __restrict__ base,
    const float* __restrict__ deltas, const uint32_t* __restrict__ histp,
    uint32_t* __restrict__ pk, uint32_t* __restrict__ cnt8,
    uint2* __restrict__ pairs8, float* __restrict__ out)
{
    int bid = blockIdx.x;
    int tid = threadIdx.x;
    if (bid < SEL_BLOCKS) {
        int e = bid & (N_ENVS - 1);
        int s = bid >> 2;
        const float4* b4 = (const float4*)base;
        const float4* d4 = (const float4*)(deltas + (size_t)e * DD);
        uint2* pp = pairs8 + (size_t)e * CAP2;
        __shared__ uint32_t s_h[256];
        __shared__ uint32_t s_scan[256];
        __shared__ uint32_t s_P, s_base;

        // Sum the 64 per-slice partials for my bin (coalesced per j).
        uint32_t sum = 0;
        #pragma unroll 8
        for (int j = 0; j < NBLK; ++j)
            sum += histp[(j * N_ENVS + e) * 256 + tid];
        s_h[tid] = sum;
        __syncthreads();
        if (tid == 0) {
            uint32_t cum = 0;
            for (int b = 255; b >= 0; --b) {
                uint32_t cc = s_h[b];
                if (cum + cc >= (uint32_t)K_SEL) {
                    s_P = (uint32_t)b;
                    if (s == 0) {
                        pk[2 * e + 0] = (uint32_t)b;
                        pk[2 * e + 1] = (uint32_t)K_SEL - cum;   // krem8 >= 1
                    }
                    break;
                }
                cum += cc;
            }
        }
        __syncthreads();
        uint32_t P = s_P;

        // Phase 1: compute keys once, keep in registers, count my matches.
        int g0 = s * 256 + tid;
        uint32_t keys[16];
        uint32_t m = 0;
        #pragma unroll
        for (int r = 0; r < 4; ++r) {
            int g = g0 + r * 16384;
            float4 bv = b4[g], dv = d4[g];
            uint32_t c0 = fkey(bv.x + dv.x), c1 = fkey(bv.y + dv.y);
            uint32_t c2 = fkey(bv.z + dv.z), c3 = fkey(bv.w + dv.w);
            keys[r*4+0]=c0; keys[r*4+1]=c1; keys[r*4+2]=c2; keys[r*4+3]=c3;
            m += ((c0>>24)==P) + ((c1>>24)==P) + ((c2>>24)==P) + ((c3>>24)==P);
        }
        // Inclusive Hillis-Steele scan over 256 threads.
        s_scan[tid] = m;
        __syncthreads();
        #pragma unroll
        for (int off = 1; off < 256; off <<= 1) {
            uint32_t v = (tid >= off) ? s_scan[tid - off] : 0u;
            __syncthreads();
            s_scan[tid] += v;
            __syncthreads();
        }
        uint32_t excl = s_scan[tid] - m;
        if (tid == 255) s_base = atomicAdd(&cnt8[e], s_scan[255]);
        __syncthreads();
        uint32_t pos = s_base + excl;

        // Phase 2: scatter straight from registers.
        #pragma unroll
        for (int r = 0; r < 4; ++r) {
            int g = g0 + r * 16384;
            #pragma unroll
            for (int j = 0; j < 4; ++j) {
                uint32_t key = keys[r * 4 + j];
                if ((key >> 24) == P) {
                    if (pos < CAP2) pp[pos] = make_uint2(key, (uint32_t)(g * 4 + j));
                    ++pos;
                }
            }
        }
    } else {
        int w = bid - SEL_BLOCKS;
        int c = w & 255;
        int h = 4 + (w >> 8);                         // bands 4..7 -> rows 64..127
        write_lgsg_band(env_idx, base, deltas, out, c, h, tid);
    }
}

// ---- K3: refine within byte-bin (bits 16-23) + exact rank select. ----
// Round-2 verified kernel, unchanged. grid 4 x 1024.
__global__ __launch_bounds__(1024) void select2_kernel(
    const uint32_t* __restrict__ pk, const uint32_t* __restrict__ cnt8,
    const uint2* __restrict__ pairs8, uint32_t* __restrict__ thrcut)
{
    int e = blockIdx.x;
    const uint2* pp = pairs8 + (size_t)e * CAP2;
    uint32_t M = cnt8[e]; if (M > CAP2) M = CAP2;
    uint32_t krem8 = pk[2 * e + 1];
    __shared__ uint32_t s_h16[256];
    __shared__ uint2    s_pairs[CAP3];
    __shared__ uint32_t s_b16, s_krem16, s_cnt;
    int tid = threadIdx.x;
    if (tid < 256) s_h16[tid] = 0;
    if (tid == 0) s_cnt = 0;
    __syncthreads();
    for (uint32_t j = tid; j < M; j += 1024)
        atomicAdd(&s_h16[(pp[j].x >> 16) & 255u], 1u);
    __syncthreads();
    if (tid == 0) {
        uint32_t cum = 0;
        for (int b = 255; b >= 0; --b) {
            uint32_t c = s_h16[b];
            if (cum + c >= krem8) { s_b16 = (uint32_t)b; s_krem16 = krem8 - cum; break; }
            cum += c;
        }
    }
    __syncthreads();
    uint32_t b16 = s_b16;
    for (uint32_t j = tid; j < M; j += 1024) {
        uint2 p = pp[j];
        if (((p.x >> 16) & 255u) == b16) {
            uint32_t pos = atomicAdd(&s_cnt, 1u);
            if (pos < CAP3) s_pairs[pos] = p;
        }
    }
    __syncthreads();
    uint32_t M2 = s_cnt; if (M2 > CAP3) M2 = CAP3;
    uint32_t target = s_krem16 - 1;                   // 0-based rank
    for (uint32_t j = tid; j < M2; j += 1024) {
        uint2 me = s_pairs[j];
        uint32_t rank = 0;
        for (uint32_t l = 0; l < M2; ++l) {
            uint2 o = s_pairs[l];
            rank += (o.x > me.x) || (o.x == me.x && o.y < me.y);
        }
        if (rank == target) {
            thrcut[2 * e + 0] = me.x;
            thrcut[2 * e + 1] = me.y;
        }
    }
}

// ---- K4: A plane only (needs thrcut). grid (256, 8) x 256. ----
__global__ __launch_bounds__(256) void k4_aplane(
    const int* __restrict__ env_idx, const float* __restrict__ base,
    const float* __restrict__ deltas, const uint32_t* __restrict__ thrcut,
    float* __restrict__ out)
{
    __shared__ int s_env[16];
    int tid = threadIdx.x;
    int h = blockIdx.y;                               // band: rows h*16..h*16+15
    if (tid < 16) s_env[tid] = env_idx[h * 16 + tid];
    int g = blockIdx.x * 256 + tid;
    uint32_t i0 = (uint32_t)g * 4u;
    float4 bv = ((const float4*)base)[g];
    nfloat4 avv[N_ENVS];
    #pragma unroll
    for (int e = 0; e < N_ENVS; ++e) {
        float4 dv = ((const float4*)(deltas + (size_t)e * DD))[g];
        uint32_t T = thrcut[2 * e], C = thrcut[2 * e + 1];
        nfloat4 lg = { bv.x + dv.x, bv.y + dv.y, bv.z + dv.z, bv.w + dv.w };
        nfloat4 sg = { sigmoidf_(lg.x), sigmoidf_(lg.y),
                       sigmoidf_(lg.z), sigmoidf_(lg.w) };
        uint32_t kx = fkey(lg.x), ky = fkey(lg.y);
        uint32_t kz = fkey(lg.z), kw = fkey(lg.w);
        nfloat4 av;
        av.x = (kx > T || (kx == T && i0 + 0u <= C)) ? sg.x : 0.0f;
        av.y = (ky > T || (ky == T && i0 + 1u <= C)) ? sg.y : 0.0f;
        av.z = (kz > T || (kz == T && i0 + 2u <= C)) ? sg.z : 0.0f;
        av.w = (kw > T || (kw == T && i0 + 3u <= C)) ? sg.w : 0.0f;
        avv[e] = av;
    }
    __syncthreads();
    nfloat4* o0 = (nfloat4*)out + g;
    #pragma unroll 4
    for (int bb = 0; bb < 16; ++bb) {
        int b = h * 16 + bb;
        int e = s_env[bb];
        nfloat4* o = o0 + (size_t)b * DD4;
        switch (e) {
        case 0:  o[0] = avv[0]; break;
        case 1:  o[0] = avv[1]; break;
        case 2:  o[0] = avv[2]; break;
        default: o[0] = avv[3]; break;
        }
    }
}

// ---- Fallback full writer (round-2 verified): all 3 planes, all rows. ----
// Used only when selection scratch lives in d_out's tail (no overlap safe).
__global__ __launch_bounds__(256) void write_bcast_kernel(
    const int* __restrict__ env_idx, const float* __restrict__ base,
    const float* __restrict__ deltas, const uint32_t* __restrict__ thrcut,
    float* __restrict__ out)
{
    __shared__ int s_env[B_DIM];
    int tid = threadIdx.x;
    if (tid < B_DIM) s_env[tid] = env_idx[tid];
    int g = blockIdx.x * 256 + tid;
    uint32_t i0 = (uint32_t)g * 4u;
    float4 bv = ((const float4*)base)[g];
    nfloat4 lgv[N_ENVS], sgv[N_ENVS], avv[N_ENVS];
    #pragma unroll
    for (int e = 0; e < N_ENVS; ++e) {
        float4 dv = ((const float4*)(deltas + (size_t)e * DD))[g];
        uint32_t T = thrcut[2 * e], C = thrcut[2 * e + 1];
        nfloat4 lg = { bv.x + dv.x, bv.y + dv.y, bv.z + dv.z, bv.w + dv.w };
        nfloat4 sg = { sigmoidf_(lg.x), sigmoidf_(lg.y),
                       sigmoidf_(lg.z), sigmoidf_(lg.w) };
        uint32_t kx = fkey(lg.x), ky = fkey(lg.y);
        uint32_t kz = fkey(lg.z), kw = fkey(lg.w);
        nfloat4 av;
        av.x = (kx > T || (kx == T && i0 + 0u <= C)) ? sg.x : 0.0f;
        av.y = (ky > T || (ky == T && i0 + 1u <= C)) ? sg.y : 0.0f;
        av.z = (kz > T || (kz == T && i0 + 2u <= C)) ? sg.z : 0.0f;
        av.w = (kw > T || (kw == T && i0 + 3u <= C)) ? sg.w : 0.0f;
        lgv[e] = lg; sgv[e] = sg; avv[e] = av;
    }
    __syncthreads();
    const int ROWS = B_DIM / 8;
    int b0 = blockIdx.y * ROWS;
    nfloat4* o0 = (nfloat4*)out + g;
    #pragma unroll 4
    for (int bb = 0; bb < ROWS; ++bb) {
        int b = b0 + bb;
        int e = s_env[b];
        nfloat4* o = o0 + (size_t)b * DD4;
        switch (e) {
        case 0: o[0] = avv[0]; o[BDD/4] = lgv[0]; o[2*(BDD/4)] = sgv[0]; break;
        case 1: o[0] = avv[1]; o[BDD/4] = lgv[1]; o[2*(BDD/4)] = sgv[1]; break;
        case 2: o[0] = avv[2]; o[BDD/4] = lgv[2]; o[2*(BDD/4)] = sgv[2]; break;
        default: o[0] = avv[3]; o[BDD/4] = lgv[3]; o[2*(BDD/4)] = sgv[3]; break;
        }
    }
}

extern "C" void kernel_launch(void* const* d_in, const int* in_sizes, int n_in,
                              void* d_out, int out_size, void* d_ws, size_t ws_size,
                              hipStream_t stream) {
    // inputs: 0=z_s (unused), 1=env_idx (int32), 2=A_base (f32), 3=A_deltas (f32)
    const int*   env_idx  = (const int*)d_in[1];
    const float* A_base   = (const float*)d_in[2];
    const float* A_deltas = (const float*)d_in[3];
    float* out = (float*)d_out;

    uint32_t* thrcut = (uint32_t*)d_ws;   // 32 B, must survive to the final writes

    bool ws_ok = (ws_size >= SEL_NEED);
    char* scratch;
    if (ws_ok) {
        scratch = (char*)d_ws;
    } else {
        // Carve selection scratch from d_out's tail. In this mode the plane
        // writes must come AFTER select2 (they'd clobber pairs8), so we fall
        // back to the non-overlapped round-2 sequence.
        size_t out_bytes = (size_t)out_size * sizeof(float);
        scratch = (char*)d_out + ((out_bytes - SEL_NEED) & ~(size_t)255);
    }
    uint32_t* pk     = (uint32_t*)(scratch + PK_OFF);
    uint32_t* cnt8   = (uint32_t*)(scratch + CNT_OFF);
    uint32_t* histp  = (uint32_t*)(scratch + HISTP_OFF);
    uint2*    pairs8 = (uint2*)   (scratch + PAIRS_OFF);

    if (ws_ok) {
        // Overlapped: selection blocks + lg/sg plane writes share launches.
        k1_hist_lgsg<<<SEL_BLOCKS + WR_BLOCKS, 256, 0, stream>>>(
            env_idx, A_base, A_deltas, histp, cnt8, out);
        k2_gather_lgsg<<<SEL_BLOCKS + WR_BLOCKS, 256, 0, stream>>>(
            env_idx, A_base, A_deltas, histp, pk, cnt8, pairs8, out);
        select2_kernel<<<N_ENVS, 1024, 0, stream>>>(pk, cnt8, pairs8, thrcut);
        k4_aplane<<<dim3(256, 8), 256, 0, stream>>>(
            env_idx, A_base, A_deltas, thrcut, out);
    } else {
        // Round-2 verified sequence (selection scratch in out-tail).
        k1_hist_lgsg<<<SEL_BLOCKS, 256, 0, stream>>>(
            env_idx, A_base, A_deltas, histp, cnt8, out);
        k2_gather_lgsg<<<SEL_BLOCKS, 256, 0, stream>>>(
            env_idx, A_base, A_deltas, histp, pk, cnt8, pairs8, out);
        select2_kernel<<<N_ENVS, 1024, 0, stream>>>(pk, cnt8, pairs8, thrcut);
        write_bcast_kernel<<<dim3(256, 8), 256, 0, stream>>>(
            env_idx, A_base, A_deltas, thrcut, out);
    }
}